// Round 7
// baseline (238.752 us; speedup 1.0000x reference)
//
#include <hip/hip_runtime.h>
#include <stdint.h>
#include <math.h>

#define BB 256
#define VV 128000
#define NV4 (VV / 4)
#define NHALF4 (NV4 / 2)  // 16000 float4 per half-row
#define CAPG 512
#define KMAX 100
#define TPB 1024
#define TPC 512
#define THR 6.0f  // capture threshold; correctness guarded by in-kernel fallback
#define LOG2E 1.4426950408889634f

// ws layout (bytes)
#define WS_CNT_OFF 0
#define WS_Z_OFF 1024
#define WS_CL_OFF 3072
#define WS_CI_OFF (3072 + BB * CAPG * 4)
#define WS_NEED (size_t)(3072 + BB * CAPG * 8)

// ---- threefry2x32, key=(0,42); partitionable 32-bit draw:
// bits[i] = out0 ^ out1 of threefry2x32(key, x0=0, x1=i). [R4+: absmax 0] ----
__device__ __forceinline__ uint32_t threefry_xor_bits(uint32_t x0, uint32_t x1) {
    const uint32_t k0 = 0u, k1 = 42u;
    const uint32_t k2 = k0 ^ k1 ^ 0x1BD11BDAu;
    uint32_t ks[3] = {k0, k1, k2};
    const int rotA[4] = {13, 15, 26, 6};
    const int rotB[4] = {17, 29, 16, 24};
    x0 += ks[0];
    x1 += ks[1];
#pragma unroll
    for (int g = 0; g < 5; g++) {
        const int* rot = (g & 1) ? rotB : rotA;
#pragma unroll
        for (int i = 0; i < 4; i++) {
            x0 += x1;
            x1 = (x1 << rot[i]) | (x1 >> (32 - rot[i]));
            x1 ^= x0;
        }
        x0 += ks[(g + 1) % 3];
        x1 += ks[(g + 2) % 3] + (uint32_t)(g + 1);
    }
    return x0 ^ x1;
}

__device__ __forceinline__ float wave_maxf(float v) {
    for (int s = 32; s > 0; s >>= 1) v = fmaxf(v, __shfl_down(v, s));
    return v;
}
__device__ __forceinline__ float wave_sumf(float v) {
    for (int s = 32; s > 0; s >>= 1) v += __shfl_down(v, s);
    return v;
}

// ---- common tail: cumsum -> masks -> gumbel -> argmax -> out[b].
// Requires >=128 threads; sort_p/sort_idx filled for ranks [0,KMAX). ----
__device__ void common_tail(int b, int tid, const float* sort_p, const int* sort_idx,
                            float* csum_s, float* red_val, int* red_idx,
                            float topp, int topk, int* out) {
    if (tid == 0) {
        float c = 0.f;
        for (int r = 0; r < KMAX; r++) {
            c += sort_p[r];
            csum_s[r] = c;
        }
    }
    __syncthreads();
    float val = -INFINITY;
    if (tid < KMAX && tid < topk) {
        float p = sort_p[tid];
        if (!(csum_s[tid] - p > topp)) {  // top-p keep condition
            float lw = logf(p);
            uint32_t idx = (uint32_t)b * (uint32_t)VV + (uint32_t)tid;
            uint32_t bits = threefry_xor_bits(0u, idx);
            uint32_t fb = (bits >> 9) | 0x3F800000u;
            float f = __uint_as_float(fb) - 1.0f;
            const float TINY = 1.17549435082228751e-38f;
            float u = fmaxf(TINY, __fadd_rn(__fmul_rn(f, 1.0f - TINY), TINY));
            float g = -logf(-logf(u));
            val = g + lw;
        }
    }
    if (tid < 128) {
        red_val[tid] = (tid < KMAX) ? val : -INFINITY;
        red_idx[tid] = tid;
    }
    __syncthreads();
    for (int s = 64; s > 0; s >>= 1) {
        if (tid < s) {
            float v1 = red_val[tid], v2 = red_val[tid + s];
            int i1 = red_idx[tid], i2 = red_idx[tid + s];
            if (v2 > v1 || (v2 == v1 && i2 < i1)) {
                red_val[tid] = v2;
                red_idx[tid] = i2;
            }
        }
        __syncthreads();
    }
    if (tid == 0) out[b] = sort_idx[red_idx[0]];
}

// ---- exact brute-force fill of sort_p/sort_idx (R3-verified; rare path) ----
template <int NT>
__device__ void fallback_fill(const float* row, float T, int tid,
                              float* wv, int* iwv, float* sort_p, int* sort_idx,
                              float* s_f /*[2]: lmax, z|bp*/, int* s_i /*[1]: bj*/) {
    const int lane = tid & 63, wave = tid >> 6;
    const int NW = NT / 64;
    float lm = -INFINITY;
    for (int j = tid; j < VV; j += NT) lm = fmaxf(lm, row[j]);
    lm = wave_maxf(lm);
    if (lane == 0) wv[wave] = lm;
    __syncthreads();
    if (tid == 0) {
        float M = wv[0];
        for (int w = 1; w < NW; w++) M = fmaxf(M, wv[w]);
        s_f[0] = M;
    }
    __syncthreads();
    const float m = s_f[0] / T;
    float zp = 0.f;
    for (int j = tid; j < VV; j += NT) zp += expf(row[j] / T - m);
    zp = wave_sumf(zp);
    __syncthreads();
    if (lane == 0) wv[wave] = zp;
    __syncthreads();
    if (tid == 0) {
        float Zs = wv[0];
        for (int w = 1; w < NW; w++) Zs += wv[w];
        s_f[1] = Zs;
    }
    __syncthreads();
    const float Z = s_f[1];
    float prevP = INFINITY;
    int prevJ = -1;
    for (int r = 0; r < KMAX; r++) {
        float bp = -1.f;
        int bj = 0x7FFFFFFF;
        for (int j = tid; j < VV; j += NT) {
            float p = expf(row[j] / T - m);
            bool elig = (p < prevP) || (p == prevP && j > prevJ);
            if (elig && (p > bp || (p == bp && j < bj))) {
                bp = p;
                bj = j;
            }
        }
        for (int s = 32; s > 0; s >>= 1) {
            float op = __shfl_down(bp, s);
            int oj = __shfl_down(bj, s);
            if (op > bp || (op == bp && oj < bj)) {
                bp = op;
                bj = oj;
            }
        }
        if (lane == 0) {
            wv[wave] = bp;
            iwv[wave] = bj;
        }
        __syncthreads();
        if (tid == 0) {
            float P = wv[0];
            int J = iwv[0];
            for (int w = 1; w < NW; w++)
                if (wv[w] > P || (wv[w] == P && iwv[w] < J)) {
                    P = wv[w];
                    J = iwv[w];
                }
            sort_p[r] = P / Z;
            sort_idx[r] = J;
            s_f[1] = P;
            s_i[0] = J;
        }
        __syncthreads();
        prevP = s_f[1];
        prevJ = s_i[0];
        __syncthreads();
    }
}

__global__ void init_kernel(int* wcnt) {
    if (threadIdx.x < BB) wcnt[threadIdx.x] = 0;
}

// ---- bulk pass: grid BB*2, each block does half a row. No LDS in hot loop.
// Z_raw = sum 2^(l*c1) (fixed reference, no overflow: |l*c1| < ~33);
// capture l >= THR into global per-row arrays. ----
__global__ __launch_bounds__(TPB, 8) void pass_kernel(
    const float* __restrict__ logits, const float* __restrict__ temps,
    int* __restrict__ wcnt, float* __restrict__ wz,
    float* __restrict__ wcl, int* __restrict__ wci) {
    __shared__ float wv[TPB / 64];
    const int blk = blockIdx.x;
    const int b = blk >> 1, half = blk & 1;
    const int tid = threadIdx.x, lane = tid & 63, wave = tid >> 6;
    const float T = temps[b];
    const float c1 = LOG2E / T;
    const float4* row4 = (const float4*)(logits + (size_t)b * VV) + half * NHALF4;
    const int base4 = half * NHALF4;

    float z = 0.f;
    int i = tid;
    for (; i + 3 * TPB < NHALF4; i += 4 * TPB) {
        float4 v0 = row4[i];
        float4 v1 = row4[i + TPB];
        float4 v2 = row4[i + 2 * TPB];
        float4 v3 = row4[i + 3 * TPB];
        float a[16] = {v0.x, v0.y, v0.z, v0.w, v1.x, v1.y, v1.z, v1.w,
                       v2.x, v2.y, v2.z, v2.w, v3.x, v3.y, v3.z, v3.w};
#pragma unroll
        for (int j = 0; j < 16; j++) {
            float l = a[j];
            z += exp2f(l * c1);
            if (l >= THR) {
                int slot = atomicAdd(&wcnt[b], 1);
                if (slot < CAPG) {
                    wcl[b * CAPG + slot] = l;
                    wci[b * CAPG + slot] = (base4 + i + (j >> 2) * TPB) * 4 + (j & 3);
                }
            }
        }
    }
    for (; i < NHALF4; i += TPB) {
        float4 v = row4[i];
        float a[4] = {v.x, v.y, v.z, v.w};
#pragma unroll
        for (int j = 0; j < 4; j++) {
            float l = a[j];
            z += exp2f(l * c1);
            if (l >= THR) {
                int slot = atomicAdd(&wcnt[b], 1);
                if (slot < CAPG) {
                    wcl[b * CAPG + slot] = l;
                    wci[b * CAPG + slot] = (base4 + i) * 4 + j;
                }
            }
        }
    }
    z = wave_sumf(z);
    if (lane == 0) wv[wave] = z;
    __syncthreads();
    if (tid == 0) {
        float Z = wv[0];
        for (int w = 1; w < TPB / 64; w++) Z += wv[w];
        wz[2 * b + half] = Z;  // deterministic: fixed slot per half, fixed-order final add
    }
}

// ---- tail: one block per row, candidates -> exact sorted top-100 -> sample ----
__global__ __launch_bounds__(TPC) void tail_kernel(
    const float* __restrict__ logits, const float* __restrict__ temps,
    const float* __restrict__ top_ps, const int* __restrict__ top_ks,
    const int* __restrict__ wcnt, const float* __restrict__ wz,
    const float* __restrict__ wcl, const int* __restrict__ wci,
    int* __restrict__ out) {
    __shared__ float cand_p[CAPG];
    __shared__ int cand_i[CAPG];
    __shared__ float sort_p[KMAX];
    __shared__ int sort_idx[KMAX];
    __shared__ float csum_s[KMAX];
    __shared__ float red_val[128];
    __shared__ int red_idx[128];
    __shared__ float wv[TPC / 64];
    __shared__ int iwv[TPC / 64];
    __shared__ float s_f[2];
    __shared__ int s_i[1];

    const int b = blockIdx.x, tid = threadIdx.x, lane = tid & 63, wave = tid >> 6;
    const float T = temps[b];
    const float c1 = LOG2E / T;
    const int cnt = wcnt[b];
    const float* row = logits + (size_t)b * VV;

    if (cnt >= KMAX && cnt <= CAPG) {
        // fast path: all >=THR captured and count>=100 => true top-100 subset,
        // and the row max is among candidates.
        const int C = cnt;
        float myl = -INFINITY;
        int myi = 0;
        if (tid < C) {
            myl = wcl[b * CAPG + tid];
            myi = wci[b * CAPG + tid];
        }
        float v = wave_maxf(myl);
        if (lane == 0) wv[wave] = v;
        __syncthreads();
        if (tid == 0) {
            float M = wv[0];
            for (int w = 1; w < TPC / 64; w++) M = fmaxf(M, wv[w]);
            s_f[0] = M;
        }
        __syncthreads();
        const float lmax = s_f[0];
        const float m = lmax / T;  // == max(l/T), matches JAX (monotone div)
        const float Z = (wz[2 * b] + wz[2 * b + 1]) * exp2f(-lmax * c1);
        float my_pn = 0.f;
        if (tid < C) {
            float x = myl / T;       // exact f32 div, as JAX
            float p = expf(x - m);   // libm expf, R4-passing sequence
            my_pn = p / Z;
            cand_p[tid] = my_pn;
            cand_i[tid] = myi;
        }
        __syncthreads();
        if (tid < C) {
            int r = 0;
            for (int c = 0; c < C; c++) {
                float pc = cand_p[c];
                int ic = cand_i[c];
                // stable descending: larger p first, tie -> smaller index first
                if (pc > my_pn || (pc == my_pn && ic < myi)) r++;
            }
            if (r < KMAX) {
                sort_p[r] = my_pn;
                sort_idx[r] = myi;
            }
        }
        __syncthreads();
    } else {
        fallback_fill<TPC>(row, T, tid, wv, iwv, sort_p, sort_idx, s_f, s_i);
    }

    common_tail(b, tid, sort_p, sort_idx, csum_s, red_val, red_idx,
                top_ps[b], top_ks[b], out);
}

// ---- fused single-kernel variant (used only if ws_size is too small) ----
__global__ __launch_bounds__(TPB) void fused_kernel(
    const float* __restrict__ logits, const float* __restrict__ temps,
    const float* __restrict__ top_ps, const int* __restrict__ top_ks,
    int* __restrict__ out) {
    __shared__ float cl[CAPG];
    __shared__ int ci[CAPG];
    __shared__ float cand_p[CAPG];
    __shared__ int cand_i[CAPG];
    __shared__ float sort_p[KMAX];
    __shared__ int sort_idx[KMAX];
    __shared__ float csum_s[KMAX];
    __shared__ float red_val[128];
    __shared__ int red_idx[128];
    __shared__ float wv[TPB / 64];
    __shared__ int iwv[TPB / 64];
    __shared__ float s_f[2];
    __shared__ int s_i[1];
    __shared__ int s_cnt;

    const int b = blockIdx.x, tid = threadIdx.x, lane = tid & 63, wave = tid >> 6;
    const float T = temps[b];
    const float c1 = LOG2E / T;
    const float* row = logits + (size_t)b * VV;
    const float4* row4 = (const float4*)row;

    if (tid == 0) s_cnt = 0;
    __syncthreads();
    float z = 0.f, lmax = -INFINITY;
    for (int i = tid; i < NV4; i += TPB) {
        float4 v = row4[i];
        float a[4] = {v.x, v.y, v.z, v.w};
#pragma unroll
        for (int j = 0; j < 4; j++) {
            float l = a[j];
            lmax = fmaxf(lmax, l);
            z += exp2f(l * c1);
            if (l >= THR) {
                int slot = atomicAdd(&s_cnt, 1);
                if (slot < CAPG) {
                    cl[slot] = l;
                    ci[slot] = i * 4 + j;
                }
            }
        }
    }
    lmax = wave_maxf(lmax);
    if (lane == 0) wv[wave] = lmax;
    __syncthreads();
    if (tid == 0) {
        float M = wv[0];
        for (int w = 1; w < TPB / 64; w++) M = fmaxf(M, wv[w]);
        s_f[0] = M;
    }
    __syncthreads();
    const float lm = s_f[0];
    z = wave_sumf(z);
    __syncthreads();
    if (lane == 0) wv[wave] = z;
    __syncthreads();
    if (tid == 0) {
        float Zs = wv[0];
        for (int w = 1; w < TPB / 64; w++) Zs += wv[w];
        s_f[1] = Zs;
    }
    __syncthreads();
    const float Zraw = s_f[1];
    const int cnt = s_cnt;
    __syncthreads();

    if (cnt >= KMAX && cnt <= CAPG) {
        const int C = cnt;
        const float m = lm / T;
        const float Z = Zraw * exp2f(-lm * c1);
        float my_pn = 0.f;
        int myi = 0;
        if (tid < C) {
            float x = cl[tid] / T;
            float p = expf(x - m);
            my_pn = p / Z;
            myi = ci[tid];
            cand_p[tid] = my_pn;
            cand_i[tid] = myi;
        }
        __syncthreads();
        if (tid < C) {
            int r = 0;
            for (int c = 0; c < C; c++) {
                float pc = cand_p[c];
                int icx = cand_i[c];
                if (pc > my_pn || (pc == my_pn && icx < myi)) r++;
            }
            if (r < KMAX) {
                sort_p[r] = my_pn;
                sort_idx[r] = myi;
            }
        }
        __syncthreads();
    } else {
        fallback_fill<TPB>(row, T, tid, wv, iwv, sort_p, sort_idx, s_f, s_i);
    }

    common_tail(b, tid, sort_p, sort_idx, csum_s, red_val, red_idx,
                top_ps[b], top_ks[b], out);
}

extern "C" void kernel_launch(void* const* d_in, const int* in_sizes, int n_in,
                              void* d_out, int out_size, void* d_ws, size_t ws_size,
                              hipStream_t stream) {
    const float* logits = (const float*)d_in[0];
    const float* temps = (const float*)d_in[1];
    const float* top_ps = (const float*)d_in[2];
    const int* top_ks = (const int*)d_in[3];
    // d_in[4] = min_ps, unused (need_min_p_sampling=False)
    int* out = (int*)d_out;

    if (ws_size >= WS_NEED) {
        char* wsb = (char*)d_ws;
        int* wcnt = (int*)(wsb + WS_CNT_OFF);
        float* wz = (float*)(wsb + WS_Z_OFF);
        float* wcl = (float*)(wsb + WS_CL_OFF);
        int* wci = (int*)(wsb + WS_CI_OFF);
        init_kernel<<<1, 256, 0, stream>>>(wcnt);
        pass_kernel<<<BB * 2, TPB, 0, stream>>>(logits, temps, wcnt, wz, wcl, wci);
        tail_kernel<<<BB, TPC, 0, stream>>>(logits, temps, top_ps, top_ks,
                                            wcnt, wz, wcl, wci, out);
    } else {
        fused_kernel<<<BB, TPB, 0, stream>>>(logits, temps, top_ps, top_ks, out);
    }
}

// Round 8
// 223.249 us; speedup vs baseline: 1.0694x; 1.0694x over previous
//
#include <hip/hip_runtime.h>
#include <stdint.h>
#include <math.h>

#define BB 256
#define VV 128000
#define NV4 (VV / 4)
#define SLICES 8
#define SLICE_E (VV / SLICES)   // 16000 elements
#define SLICE_F4 (SLICE_E / 4)  // 4000 float4
#define SL 320                  // per-slice candidate slots (E[cnt]=21.6, sigma=4.6)
#define CAPG 512                // total candidate cap in tail
#define KMAX 100
#define TPP 256                 // pass block
#define TPC 512                 // tail block
#define TPB 1024                // fused fallback block
#define THR 6.0f                // capture threshold; guarded by exact fallback
#define LOG2E 1.4426950408889634f

// ws layout (bytes); no initialization needed (plain stores, no counters from 0xAA)
#define WS_CNT_OFF 0                         // 2048 ints
#define WS_Z_OFF 8192                        // 2048 floats
#define WS_CL_OFF 16384                      // 2048*SL floats
#define WS_CI_OFF (16384 + 2048 * SL * 4)    // 2048*SL ints
#define WS_NEED (size_t)(16384 + (size_t)2048 * SL * 8)

// ---- threefry2x32, key=(0,42); partitionable 32-bit draw:
// bits[i] = out0 ^ out1 of threefry2x32(key, x0=0, x1=i). [R4+: absmax 0] ----
__device__ __forceinline__ uint32_t threefry_xor_bits(uint32_t x0, uint32_t x1) {
    const uint32_t k0 = 0u, k1 = 42u;
    const uint32_t k2 = k0 ^ k1 ^ 0x1BD11BDAu;
    uint32_t ks[3] = {k0, k1, k2};
    const int rotA[4] = {13, 15, 26, 6};
    const int rotB[4] = {17, 29, 16, 24};
    x0 += ks[0];
    x1 += ks[1];
#pragma unroll
    for (int g = 0; g < 5; g++) {
        const int* rot = (g & 1) ? rotB : rotA;
#pragma unroll
        for (int i = 0; i < 4; i++) {
            x0 += x1;
            x1 = (x1 << rot[i]) | (x1 >> (32 - rot[i]));
            x1 ^= x0;
        }
        x0 += ks[(g + 1) % 3];
        x1 += ks[(g + 2) % 3] + (uint32_t)(g + 1);
    }
    return x0 ^ x1;
}

__device__ __forceinline__ float wave_maxf(float v) {
    for (int s = 32; s > 0; s >>= 1) v = fmaxf(v, __shfl_down(v, s));
    return v;
}
__device__ __forceinline__ float wave_sumf(float v) {
    for (int s = 32; s > 0; s >>= 1) v += __shfl_down(v, s);
    return v;
}

// ---- common tail: cumsum -> masks -> gumbel -> argmax -> out[b]. ----
__device__ void common_tail(int b, int tid, const float* sort_p, const int* sort_idx,
                            float* csum_s, float* red_val, int* red_idx,
                            float topp, int topk, int* out) {
    if (tid == 0) {
        float c = 0.f;
        for (int r = 0; r < KMAX; r++) {
            c += sort_p[r];
            csum_s[r] = c;
        }
    }
    __syncthreads();
    float val = -INFINITY;
    if (tid < KMAX && tid < topk) {
        float p = sort_p[tid];
        if (!(csum_s[tid] - p > topp)) {  // top-p keep condition
            float lw = logf(p);
            uint32_t idx = (uint32_t)b * (uint32_t)VV + (uint32_t)tid;
            uint32_t bits = threefry_xor_bits(0u, idx);
            uint32_t fb = (bits >> 9) | 0x3F800000u;
            float f = __uint_as_float(fb) - 1.0f;
            const float TINY = 1.17549435082228751e-38f;
            float u = fmaxf(TINY, __fadd_rn(__fmul_rn(f, 1.0f - TINY), TINY));
            float g = -logf(-logf(u));
            val = g + lw;
        }
    }
    if (tid < 128) {
        red_val[tid] = (tid < KMAX) ? val : -INFINITY;
        red_idx[tid] = tid;
    }
    __syncthreads();
    for (int s = 64; s > 0; s >>= 1) {
        if (tid < s) {
            float v1 = red_val[tid], v2 = red_val[tid + s];
            int i1 = red_idx[tid], i2 = red_idx[tid + s];
            if (v2 > v1 || (v2 == v1 && i2 < i1)) {
                red_val[tid] = v2;
                red_idx[tid] = i2;
            }
        }
        __syncthreads();
    }
    if (tid == 0) out[b] = sort_idx[red_idx[0]];
}

// ---- exact brute-force fill of sort_p/sort_idx (R3-verified; rare path) ----
template <int NT>
__device__ void fallback_fill(const float* row, float T, int tid,
                              float* wv, int* iwv, float* sort_p, int* sort_idx,
                              float* s_f, int* s_i) {
    const int lane = tid & 63, wave = tid >> 6;
    const int NW = NT / 64;
    float lm = -INFINITY;
    for (int j = tid; j < VV; j += NT) lm = fmaxf(lm, row[j]);
    lm = wave_maxf(lm);
    if (lane == 0) wv[wave] = lm;
    __syncthreads();
    if (tid == 0) {
        float M = wv[0];
        for (int w = 1; w < NW; w++) M = fmaxf(M, wv[w]);
        s_f[0] = M;
    }
    __syncthreads();
    const float m = s_f[0] / T;
    float zp = 0.f;
    for (int j = tid; j < VV; j += NT) zp += expf(row[j] / T - m);
    zp = wave_sumf(zp);
    __syncthreads();
    if (lane == 0) wv[wave] = zp;
    __syncthreads();
    if (tid == 0) {
        float Zs = wv[0];
        for (int w = 1; w < NW; w++) Zs += wv[w];
        s_f[1] = Zs;
    }
    __syncthreads();
    const float Z = s_f[1];
    float prevP = INFINITY;
    int prevJ = -1;
    for (int r = 0; r < KMAX; r++) {
        float bp = -1.f;
        int bj = 0x7FFFFFFF;
        for (int j = tid; j < VV; j += NT) {
            float p = expf(row[j] / T - m);
            bool elig = (p < prevP) || (p == prevP && j > prevJ);
            if (elig && (p > bp || (p == bp && j < bj))) {
                bp = p;
                bj = j;
            }
        }
        for (int s = 32; s > 0; s >>= 1) {
            float op = __shfl_down(bp, s);
            int oj = __shfl_down(bj, s);
            if (op > bp || (op == bp && oj < bj)) {
                bp = op;
                bj = oj;
            }
        }
        if (lane == 0) {
            wv[wave] = bp;
            iwv[wave] = bj;
        }
        __syncthreads();
        if (tid == 0) {
            float P = wv[0];
            int J = iwv[0];
            for (int w = 1; w < NW; w++)
                if (wv[w] > P || (wv[w] == P && iwv[w] < J)) {
                    P = wv[w];
                    J = iwv[w];
                }
            sort_p[r] = P / Z;
            sort_idx[r] = J;
            s_f[1] = P;
            s_i[0] = J;
        }
        __syncthreads();
        prevP = s_f[1];
        prevJ = s_i[0];
        __syncthreads();
    }
}

// ---- bulk pass: grid BB*SLICES blocks x 256 thr, 8 blocks/CU (32 waves/CU).
// Hot loop: 4 independent float4 loads joined by an fmax tree (blocks load
// sinking), 16x exp2 into Z, capture gated on batch max (rare). No atomics,
// no LDS in the common path; per-block results plain-stored (no init). ----
__global__ __launch_bounds__(TPP, 8) void pass_kernel(
    const float* __restrict__ logits, const float* __restrict__ temps,
    int* __restrict__ wcnt, float* __restrict__ wz,
    float* __restrict__ wcl, int* __restrict__ wci) {
    __shared__ float scl[SL];
    __shared__ int sci[SL];
    __shared__ float wvv[TPP / 64];
    __shared__ int s_cnt;

    const int blk = blockIdx.x;
    const int b = blk >> 3, sl = blk & 7;
    const int tid = threadIdx.x, lane = tid & 63, wave = tid >> 6;
    const float T = temps[b];
    const float c1 = LOG2E / T;
    const float4* row4 = (const float4*)(logits + (size_t)b * VV) + sl * SLICE_F4;
    const int ebase = sl * SLICE_E;

    if (tid == 0) s_cnt = 0;
    __syncthreads();

    float z = 0.f;
    int i = tid;
    for (; i + 3 * TPP < SLICE_F4; i += 4 * TPP) {
        float4 v0 = row4[i];
        float4 v1 = row4[i + TPP];
        float4 v2 = row4[i + 2 * TPP];
        float4 v3 = row4[i + 3 * TPP];
        // join all 4 loads early: batch max feeds the capture gate
        float b0 = fmaxf(fmaxf(v0.x, v0.y), fmaxf(v0.z, v0.w));
        float b1 = fmaxf(fmaxf(v1.x, v1.y), fmaxf(v1.z, v1.w));
        float b2 = fmaxf(fmaxf(v2.x, v2.y), fmaxf(v2.z, v2.w));
        float b3 = fmaxf(fmaxf(v3.x, v3.y), fmaxf(v3.z, v3.w));
        float bmax = fmaxf(fmaxf(b0, b1), fmaxf(b2, b3));
        float e0 = (exp2f(v0.x * c1) + exp2f(v0.y * c1)) + (exp2f(v0.z * c1) + exp2f(v0.w * c1));
        float e1 = (exp2f(v1.x * c1) + exp2f(v1.y * c1)) + (exp2f(v1.z * c1) + exp2f(v1.w * c1));
        float e2 = (exp2f(v2.x * c1) + exp2f(v2.y * c1)) + (exp2f(v2.z * c1) + exp2f(v2.w * c1));
        float e3 = (exp2f(v3.x * c1) + exp2f(v3.y * c1)) + (exp2f(v3.z * c1) + exp2f(v3.w * c1));
        z += (e0 + e1) + (e2 + e3);
        if (bmax >= THR) {  // rare (~1% of batches)
            float a[16] = {v0.x, v0.y, v0.z, v0.w, v1.x, v1.y, v1.z, v1.w,
                           v2.x, v2.y, v2.z, v2.w, v3.x, v3.y, v3.z, v3.w};
#pragma unroll
            for (int j = 0; j < 16; j++) {
                if (a[j] >= THR) {
                    int slot = atomicAdd(&s_cnt, 1);
                    if (slot < SL) {
                        scl[slot] = a[j];
                        sci[slot] = ebase + (i + (j >> 2) * TPP) * 4 + (j & 3);
                    }
                }
            }
        }
    }
    for (; i < SLICE_F4; i += TPP) {
        float4 v = row4[i];
        float bmax = fmaxf(fmaxf(v.x, v.y), fmaxf(v.z, v.w));
        z += (exp2f(v.x * c1) + exp2f(v.y * c1)) + (exp2f(v.z * c1) + exp2f(v.w * c1));
        if (bmax >= THR) {
            float a[4] = {v.x, v.y, v.z, v.w};
#pragma unroll
            for (int j = 0; j < 4; j++) {
                if (a[j] >= THR) {
                    int slot = atomicAdd(&s_cnt, 1);
                    if (slot < SL) {
                        scl[slot] = a[j];
                        sci[slot] = ebase + i * 4 + j;
                    }
                }
            }
        }
    }
    z = wave_sumf(z);
    if (lane == 0) wvv[wave] = z;
    __syncthreads();
    if (tid == 0) {
        float Zs = wvv[0];
        for (int w = 1; w < TPP / 64; w++) Zs += wvv[w];
        wz[blk] = Zs;         // deterministic: fixed slot, fixed-order add
        wcnt[blk] = s_cnt;    // raw count (tail detects overflow)
    }
    const int n = (s_cnt < SL) ? s_cnt : SL;
    for (int k = tid; k < n; k += TPP) {
        wcl[blk * SL + k] = scl[k];
        wci[blk * SL + k] = sci[k];
    }
}

// ---- tail: one block per row; gather 8 slices -> exact top-100 -> sample ----
__global__ __launch_bounds__(TPC) void tail_kernel(
    const float* __restrict__ logits, const float* __restrict__ temps,
    const float* __restrict__ top_ps, const int* __restrict__ top_ks,
    const int* __restrict__ wcnt, const float* __restrict__ wz,
    const float* __restrict__ wcl, const int* __restrict__ wci,
    int* __restrict__ out) {
    __shared__ float cand_l[CAPG];
    __shared__ float cand_p[CAPG];
    __shared__ int cand_i[CAPG];
    __shared__ float sort_p[KMAX];
    __shared__ int sort_idx[KMAX];
    __shared__ float csum_s[KMAX];
    __shared__ float red_val[128];
    __shared__ int red_idx[128];
    __shared__ float wv[TPC / 64];
    __shared__ int iwv[TPC / 64];
    __shared__ float s_f[2];
    __shared__ int s_i[1];
    __shared__ int soff[SLICES];
    __shared__ int scnts[SLICES];
    __shared__ int s_stat;  // 0 = fast ok, 1 = fallback

    const int b = blockIdx.x, tid = threadIdx.x, lane = tid & 63, wave = tid >> 6;
    const float T = temps[b];
    const float c1 = LOG2E / T;
    const float* row = logits + (size_t)b * VV;

    if (tid == 0) {
        int o = 0, bad = 0;
        for (int s = 0; s < SLICES; s++) {
            int c = wcnt[b * SLICES + s];
            scnts[s] = c;
            soff[s] = o;
            o += c;
            if (c > SL) bad = 1;
        }
        if (o < KMAX || o > CAPG) bad = 1;
        s_i[0] = o;
        s_stat = bad;
    }
    __syncthreads();
    const int C = s_i[0];
    const int bad = s_stat;

    if (!bad) {
        // gather candidates (order within slice arbitrary; ranks are unique
        // under the (p desc, idx asc) total order, so output is deterministic)
        for (int s = 0; s < SLICES; s++) {
            const int base = (b * SLICES + s) * SL, o = soff[s], c = scnts[s];
            for (int k = tid; k < c; k += TPC) {
                cand_l[o + k] = wcl[base + k];
                cand_i[o + k] = wci[base + k];
            }
        }
        __syncthreads();
        float myl = -INFINITY;
        int myi = 0;
        if (tid < C) {
            myl = cand_l[tid];
            myi = cand_i[tid];
        }
        float v = wave_maxf(myl);
        if (lane == 0) wv[wave] = v;
        __syncthreads();
        if (tid == 0) {
            float M = wv[0];
            for (int w = 1; w < TPC / 64; w++) M = fmaxf(M, wv[w]);
            s_f[0] = M;
        }
        __syncthreads();
        const float lmax = s_f[0];       // true row max (C>=100 => max >= THR captured)
        const float m = lmax / T;        // == max(l/T): monotone f32 div
        float Zraw;
        if (tid == 0) {
            Zraw = 0.f;
            for (int s = 0; s < SLICES; s++) Zraw += wz[b * SLICES + s];  // fixed order
            s_f[1] = Zraw;
        }
        __syncthreads();
        const float Z = s_f[1] * exp2f(-lmax * c1);
        float my_pn = 0.f;
        if (tid < C) {
            float x = myl / T;      // exact f32 div, as JAX
            float p = expf(x - m);  // libm expf, R4-passing sequence
            my_pn = p / Z;
            cand_p[tid] = my_pn;
        }
        __syncthreads();
        if (tid < C) {
            int r = 0;
            for (int c = 0; c < C; c++) {
                float pc = cand_p[c];
                int ic = cand_i[c];
                if (pc > my_pn || (pc == my_pn && ic < myi)) r++;
            }
            if (r < KMAX) {
                sort_p[r] = my_pn;
                sort_idx[r] = myi;
            }
        }
        __syncthreads();
    } else {
        fallback_fill<TPC>(row, T, tid, wv, iwv, sort_p, sort_idx, s_f, s_i);
    }

    common_tail(b, tid, sort_p, sort_idx, csum_s, red_val, red_idx,
                top_ps[b], top_ks[b], out);
}

// ---- fused single-kernel variant (only if ws_size too small) ----
__global__ __launch_bounds__(TPB) void fused_kernel(
    const float* __restrict__ logits, const float* __restrict__ temps,
    const float* __restrict__ top_ps, const int* __restrict__ top_ks,
    int* __restrict__ out) {
    __shared__ float cl[CAPG];
    __shared__ int ci[CAPG];
    __shared__ float cand_p[CAPG];
    __shared__ int cand_i[CAPG];
    __shared__ float sort_p[KMAX];
    __shared__ int sort_idx[KMAX];
    __shared__ float csum_s[KMAX];
    __shared__ float red_val[128];
    __shared__ int red_idx[128];
    __shared__ float wv[TPB / 64];
    __shared__ int iwv[TPB / 64];
    __shared__ float s_f[2];
    __shared__ int s_i[1];
    __shared__ int s_cnt;

    const int b = blockIdx.x, tid = threadIdx.x, lane = tid & 63, wave = tid >> 6;
    const float T = temps[b];
    const float c1 = LOG2E / T;
    const float* row = logits + (size_t)b * VV;
    const float4* row4 = (const float4*)row;

    if (tid == 0) s_cnt = 0;
    __syncthreads();
    float z = 0.f, lmax = -INFINITY;
    for (int i = tid; i < NV4; i += TPB) {
        float4 v = row4[i];
        float a[4] = {v.x, v.y, v.z, v.w};
#pragma unroll
        for (int j = 0; j < 4; j++) {
            float l = a[j];
            lmax = fmaxf(lmax, l);
            z += exp2f(l * c1);
            if (l >= THR) {
                int slot = atomicAdd(&s_cnt, 1);
                if (slot < CAPG) {
                    cl[slot] = l;
                    ci[slot] = i * 4 + j;
                }
            }
        }
    }
    lmax = wave_maxf(lmax);
    if (lane == 0) wv[wave] = lmax;
    __syncthreads();
    if (tid == 0) {
        float M = wv[0];
        for (int w = 1; w < TPB / 64; w++) M = fmaxf(M, wv[w]);
        s_f[0] = M;
    }
    __syncthreads();
    const float lm = s_f[0];
    z = wave_sumf(z);
    __syncthreads();
    if (lane == 0) wv[wave] = z;
    __syncthreads();
    if (tid == 0) {
        float Zs = wv[0];
        for (int w = 1; w < TPB / 64; w++) Zs += wv[w];
        s_f[1] = Zs;
    }
    __syncthreads();
    const float Zraw = s_f[1];
    const int cnt = s_cnt;
    __syncthreads();

    if (cnt >= KMAX && cnt <= CAPG) {
        const int C = cnt;
        const float m = lm / T;
        const float Z = Zraw * exp2f(-lm * c1);
        float my_pn = 0.f;
        int myi = 0;
        if (tid < C) {
            float x = cl[tid] / T;
            float p = expf(x - m);
            my_pn = p / Z;
            myi = ci[tid];
            cand_p[tid] = my_pn;
            cand_i[tid] = myi;
        }
        __syncthreads();
        if (tid < C) {
            int r = 0;
            for (int c = 0; c < C; c++) {
                float pc = cand_p[c];
                int icx = cand_i[c];
                if (pc > my_pn || (pc == my_pn && icx < myi)) r++;
            }
            if (r < KMAX) {
                sort_p[r] = my_pn;
                sort_idx[r] = myi;
            }
        }
        __syncthreads();
    } else {
        fallback_fill<TPB>(row, T, tid, wv, iwv, sort_p, sort_idx, s_f, s_i);
    }

    common_tail(b, tid, sort_p, sort_idx, csum_s, red_val, red_idx,
                top_ps[b], top_ks[b], out);
}

extern "C" void kernel_launch(void* const* d_in, const int* in_sizes, int n_in,
                              void* d_out, int out_size, void* d_ws, size_t ws_size,
                              hipStream_t stream) {
    const float* logits = (const float*)d_in[0];
    const float* temps = (const float*)d_in[1];
    const float* top_ps = (const float*)d_in[2];
    const int* top_ks = (const int*)d_in[3];
    // d_in[4] = min_ps, unused (need_min_p_sampling=False)
    int* out = (int*)d_out;

    if (ws_size >= WS_NEED) {
        char* wsb = (char*)d_ws;
        int* wcnt = (int*)(wsb + WS_CNT_OFF);
        float* wz = (float*)(wsb + WS_Z_OFF);
        float* wcl = (float*)(wsb + WS_CL_OFF);
        int* wci = (int*)(wsb + WS_CI_OFF);
        pass_kernel<<<BB * SLICES, TPP, 0, stream>>>(logits, temps, wcnt, wz, wcl, wci);
        tail_kernel<<<BB, TPC, 0, stream>>>(logits, temps, top_ps, top_ks,
                                            wcnt, wz, wcl, wci, out);
    } else {
        fused_kernel<<<BB, TPB, 0, stream>>>(logits, temps, top_ps, top_ks, out);
    }
}